// Round 1
// 283.821 us; speedup vs baseline: 1.0518x; 1.0518x over previous
//
#include <hip/hip_runtime.h>
#include <hip/hip_bf16.h>

#define BATCH 16
#define CIN   512
#define HW    3136
#define CM    512
#define CN    128

typedef short short8 __attribute__((ext_vector_type(8)));
typedef float f32x4  __attribute__((ext_vector_type(4)));

#define MFMA(a,b,c) __builtin_amdgcn_mfma_f32_16x16x32_bf16((a),(b),(c),0,0,0)

// convert 8 consecutive fp32 -> 8 bf16, store as one 16B chunk (LDS or global)
__device__ __forceinline__ void cvt_store8(__bf16* dst, const float* src) {
  const f32x4 a = *(const f32x4*)src;
  const f32x4 b = *(const f32x4*)(src + 4);
  __attribute__((aligned(16))) __bf16 t[8];
  t[0] = (__bf16)a[0]; t[1] = (__bf16)a[1]; t[2] = (__bf16)a[2]; t[3] = (__bf16)a[3];
  t[4] = (__bf16)b[0]; t[5] = (__bf16)b[1]; t[6] = (__bf16)b[2]; t[7] = (__bf16)b[3];
  *(uint4*)dst = *(uint4*)t;
}

// async 16B global->LDS copy (gfx950 global_load_lds_dwordx4)
__device__ __forceinline__ void load_lds16(const void* g, void* l) {
  __builtin_amdgcn_global_load_lds(
      (const __attribute__((address_space(1))) unsigned int*)g,
      (__attribute__((address_space(3))) unsigned int*)l, 16, 0, 0);
}

// ---------------------------------------------------------------------------
// Kernel 0: pre-convert (wB|wV) fp32 -> bf16 LDS tile images.
// 8 images (one per K-step of 64), each [256 rows][72 cols] bf16 = 36864 B,
// exactly the LDS byte layout conv_bv_kernel's fragment reads expect.
// ---------------------------------------------------------------------------
__global__ __launch_bounds__(256) void prep_w_kernel(
    const float* __restrict__ wB, const float* __restrict__ wV,
    __bf16* __restrict__ Wimg)
{
  const int k0  = blockIdx.x >> 2;                       // 0..7
  const int row = (blockIdx.x & 3) * 64 + (threadIdx.x >> 2);  // 0..255
  const int c0  = (threadIdx.x & 3) * 16;                // 0,16,32,48
  const float* src = (row < 128) ? (wB + (size_t)row * CIN)
                                 : (wV + (size_t)(row - 128) * CIN);
  src += k0 * 64 + c0;
  __bf16* dst = Wimg + (size_t)k0 * 18432 + row * 72 + c0;
  cvt_store8(dst, src);
  cvt_store8(dst + 8, src + 8);
}

// ---------------------------------------------------------------------------
// Kernel 1: conv (wB|wV) @ x + bias, x transposed IN-LDS (XOR-octet swizzle),
// fused V-softmax (transposed attVT out) and fused B-softmax row sums (atomics).
//   BVB[b][n][s]   raw B-half conv out (bf16)
//   attVT[b][s][n] softmaxed V-half, transposed (bf16)
//   bsum[b][n]     += sum_s exp(BVB[b][n][s])   (fp32, atomic)
// block: 64 s-cols x 256 channels; waves 0,1 = B half; waves 2,3 = V half.
// W staged via async global_load_lds from pre-built bf16 images (L2-hot);
// x staged via one-step-ahead register prefetch + swizzled pair-dword writes.
// ---------------------------------------------------------------------------
__global__ __launch_bounds__(256) void conv_bv_kernel(
    const float* __restrict__ x,
    const __bf16* __restrict__ Wimg,
    const float* __restrict__ bB, const float* __restrict__ bV,
    __bf16* __restrict__ BVB, __bf16* __restrict__ attVT,
    float* __restrict__ bsum)
{
  const int s0  = blockIdx.x * 64;
  const int b   = blockIdx.y;
  const int tid = threadIdx.x;
  const int lane = tid & 63, w = tid >> 6;
  const int l15  = lane & 15, q = lane >> 4;

  __shared__ __attribute__((aligned(16))) char smem[46080]; // Wt 36864 | Xt 9216
  __bf16* Wt = (__bf16*)smem;            // [256][72]  (n-major, k-contig)
  __bf16* Xt = (__bf16*)(smem + 36864);  // [64][72]   (s-major, XOR-swizzled octets)
  __bf16* T  = (__bf16*)smem;            // [64][136]  epilogue alias
  __shared__ float Vm[2][64];
  __shared__ float Vs[2][64];

  f32x4 acc[4][4] = {};
  const float* xb = x + (size_t)b*CIN*HW + s0;
  const int colg = tid & 7;               // X s-octet
  const int cl = 2*(tid >> 3);            // even c_local (pair cl, cl+1)
  const int xoff = ((cl >> 3) ^ colg)*8 + (cl & 7);  // swizzled octet slot (dword aligned)

  // --- prologue: prefetch X tile for k0=0 into registers
  f32x4 pa0, pa1, pb0, pb1;
  {
    const float* r0 = xb + (size_t)cl*HW + colg*8;
    const float* r1 = r0 + HW;
    pa0 = *(const f32x4*)r0; pa1 = *(const f32x4*)(r0 + 4);
    pb0 = *(const f32x4*)r1; pb1 = *(const f32x4*)(r1 + 4);
  }

  for (int k0 = 0; k0 < CIN; k0 += 64) {
    // write Xt from prefetched registers (prev end-barrier guarantees Xt free)
    {
      float va[8] = {pa0[0],pa0[1],pa0[2],pa0[3],pa1[0],pa1[1],pa1[2],pa1[3]};
      float vb[8] = {pb0[0],pb0[1],pb0[2],pb0[3],pb1[0],pb1[1],pb1[2],pb1[3]};
      #pragma unroll
      for (int j = 0; j < 8; ++j) {
        int s = colg*8 + j;
        __attribute__((aligned(4))) __bf16 pairv[2] = { (__bf16)va[j], (__bf16)vb[j] };
        *(unsigned int*)&Xt[s*72 + xoff] = *(unsigned int*)pairv;
      }
    }
    // async-stage W image (36864 B = 9 x 16B chunks per thread, no VALU)
    {
      const char* wsrc = (const char*)Wimg + (size_t)(k0 >> 6)*36864 + tid*16;
      char* wdst = (char*)Wt + tid*16;
      #pragma unroll
      for (int i = 0; i < 9; ++i)
        load_lds16(wsrc + i*4096, wdst + i*4096);
    }
    // issue X prefetch for next step (drains at the same barrier; latency
    // overlaps the W DMA and other blocks' compute)
    if (k0 + 64 < CIN) {
      const float* r0 = xb + (size_t)(k0 + 64 + cl)*HW + colg*8;
      const float* r1 = r0 + HW;
      pa0 = *(const f32x4*)r0; pa1 = *(const f32x4*)(r0 + 4);
      pb0 = *(const f32x4*)r1; pb1 = *(const f32x4*)(r1 + 4);
    }
    __syncthreads();
    #pragma unroll
    for (int kk = 0; kk < 2; ++kk) {
      short8 a[4], bb[4];
      #pragma unroll
      for (int mi = 0; mi < 4; ++mi)
        a[mi] = *(short8*)&Wt[(w*64 + mi*16 + l15)*72 + kk*32 + q*8];
      #pragma unroll
      for (int si = 0; si < 4; ++si) {
        int s = si*16 + l15;
        int oct = (kk*4 + q) ^ (si*2 + (l15 >> 3));
        bb[si] = *(short8*)&Xt[s*72 + oct*8];
      }
      #pragma unroll
      for (int mi = 0; mi < 4; ++mi)
        #pragma unroll
        for (int si = 0; si < 4; ++si)
          acc[mi][si] = MFMA(a[mi], bb[si], acc[mi][si]);
    }
    __syncthreads();
  }

  float bias[4][4];
  #pragma unroll
  for (int mi = 0; mi < 4; ++mi)
    #pragma unroll
    for (int r = 0; r < 4; ++r) {
      int nch = w*64 + mi*16 + q*4 + r;
      bias[mi][r] = (nch < CN) ? bB[nch] : bV[nch - CN];
    }

  if (w < 2) {
    // B half: write raw bf16 rows + accumulate per-n sum of exp (no max needed:
    // |v| <~ 5, exp safe in fp32; matches h_gemm's exp of the bf16-rounded value)
    const size_t outb = (size_t)b * CN * HW;
    float psum[4][4] = {};
    #pragma unroll
    for (int mi = 0; mi < 4; ++mi)
      #pragma unroll
      for (int si = 0; si < 4; ++si) {
        int s = s0 + si*16 + l15;
        #pragma unroll
        for (int r = 0; r < 4; ++r) {
          int nch = w*64 + mi*16 + q*4 + r;
          __bf16 bv = (__bf16)(acc[mi][si][r] + bias[mi][r]);
          BVB[outb + (size_t)nch*HW + s] = bv;
          psum[mi][r] += __expf((float)bv);
        }
      }
    #pragma unroll
    for (int mi = 0; mi < 4; ++mi)
      #pragma unroll
      for (int r = 0; r < 4; ++r) {
        float v = psum[mi][r];
        v += __shfl_xor(v, 1); v += __shfl_xor(v, 2);
        v += __shfl_xor(v, 4); v += __shfl_xor(v, 8);
        if (l15 == 0) {
          int nch = w*64 + mi*16 + q*4 + r;
          atomicAdd(&bsum[b*CN + nch], v);
        }
      }
  } else {
    // V half: per-s max over its 128 V channels
    #pragma unroll
    for (int si = 0; si < 4; ++si) {
      float m = -1e30f;
      #pragma unroll
      for (int mi = 0; mi < 4; ++mi)
        #pragma unroll
        for (int r = 0; r < 4; ++r)
          m = fmaxf(m, acc[mi][si][r] + bias[mi][r]);
      m = fmaxf(m, __shfl_xor(m, 16));
      m = fmaxf(m, __shfl_xor(m, 32));
      if (q == 0) Vm[w-2][si*16 + l15] = m;
    }
  }
  __syncthreads();
  if (w >= 2) {
    #pragma unroll
    for (int si = 0; si < 4; ++si) {
      int idx = si*16 + l15;
      float ms = fmaxf(Vm[0][idx], Vm[1][idx]);
      float ssum = 0.f;
      #pragma unroll
      for (int mi = 0; mi < 4; ++mi)
        #pragma unroll
        for (int r = 0; r < 4; ++r) {
          float e = __expf(acc[mi][si][r] + bias[mi][r] - ms);
          acc[mi][si][r] = e;
          ssum += e;
        }
      ssum += __shfl_xor(ssum, 16);
      ssum += __shfl_xor(ssum, 32);
      if (q == 0) Vs[w-2][idx] = ssum;
    }
  }
  __syncthreads();
  if (w >= 2) {
    #pragma unroll
    for (int si = 0; si < 4; ++si) {
      int idx = si*16 + l15;
      float inv = 1.0f / (Vs[0][idx] + Vs[1][idx]);
      #pragma unroll
      for (int mi = 0; mi < 4; ++mi)
        #pragma unroll
        for (int r = 0; r < 4; ++r) {
          int j = (w-2)*64 + mi*16 + q*4 + r;
          T[idx*136 + j] = (__bf16)(acc[mi][si][r] * inv);
        }
    }
  }
  __syncthreads();
  __bf16* dst = attVT + ((size_t)b*HW + s0)*CN;
  #pragma unroll
  for (int k = 0; k < 4; ++k) {
    int chunk = tid + 256*k;
    int row = chunk >> 4, oct = chunk & 15;
    *(uint4*)&dst[(size_t)row*CN + oct*8] = *(uint4*)&T[row*136 + oct*8];
  }
}

// ---------------------------------------------------------------------------
// Kernel 2: H[b][c][n] += sum_s x[b][c][s] * (exp(BVB[n][s]) / bsum[n])
// tile 128c x 128n, split-K=7, fp32 x converted + softmax applied at staging
// ---------------------------------------------------------------------------
__global__ __launch_bounds__(256) void h_gemm_kernel(
    const float* __restrict__ x, const __bf16* __restrict__ BVB,
    const float* __restrict__ bsum, float* __restrict__ H)
{
  const int c0 = blockIdx.x * 128, b = blockIdx.y, kc = blockIdx.z;
  const int tid = threadIdx.x, lane = tid & 63, w = tid >> 6;
  const int l15 = lane & 15, q = lane >> 4;

  __shared__ __attribute__((aligned(16))) __bf16 At[128*72];  // x tile [c][s]
  __shared__ __attribute__((aligned(16))) __bf16 Bt[128*72];  // attB tile [n][s]
  f32x4 acc[8][2] = {};

  const float* xb = x + ((size_t)b*CIN + c0)*HW;
  const __bf16* ab = BVB + (size_t)b*CN*HW;
  const float* bsb = bsum + b*CN;
  const int colg = tid & 7, row0 = tid >> 3;

  float irow[4];
  #pragma unroll
  for (int p = 0; p < 4; ++p) irow[p] = 1.0f / bsb[row0 + 32*p];

  for (int ki = 0; ki < 7; ++ki) {
    int k0 = kc*448 + ki*64;
    #pragma unroll
    for (int p = 0; p < 4; ++p) {
      int row = row0 + 32*p;
      cvt_store8(&At[row*72 + colg*8], xb + (size_t)row*HW + k0 + colg*8);
    }
    #pragma unroll
    for (int p = 0; p < 4; ++p) {
      int row = row0 + 32*p;
      uint4 rawv = *(const uint4*)(ab + (size_t)row*HW + k0 + colg*8);
      const __bf16* v = (const __bf16*)&rawv;
      __attribute__((aligned(16))) __bf16 t[8];
      #pragma unroll
      for (int j = 0; j < 8; ++j)
        t[j] = (__bf16)(__expf((float)v[j]) * irow[p]);
      *(uint4*)&Bt[row*72 + colg*8] = *(uint4*)t;
    }
    __syncthreads();
    #pragma unroll
    for (int kk = 0; kk < 2; ++kk) {
      short8 a[8], bb[2];
      #pragma unroll
      for (int mi = 0; mi < 8; ++mi)
        a[mi] = *(short8*)&At[(mi*16 + l15)*72 + kk*32 + q*8];
      #pragma unroll
      for (int ni = 0; ni < 2; ++ni)
        bb[ni] = *(short8*)&Bt[(w*32 + ni*16 + l15)*72 + kk*32 + q*8];
      #pragma unroll
      for (int mi = 0; mi < 8; ++mi)
        #pragma unroll
        for (int ni = 0; ni < 2; ++ni)
          acc[mi][ni] = MFMA(a[mi], bb[ni], acc[mi][ni]);
    }
    __syncthreads();
  }

  float* Hb = H + (size_t)b*CIN*CN;
  #pragma unroll
  for (int mi = 0; mi < 8; ++mi)
    #pragma unroll
    for (int ni = 0; ni < 2; ++ni)
      #pragma unroll
      for (int r = 0; r < 4; ++r) {
        int c = c0 + mi*16 + q*4 + r;
        int n = w*32 + ni*16 + l15;
        atomicAdd(&Hb[c*CN + n], acc[mi][ni][r]);
      }
}

// ---------------------------------------------------------------------------
// Kernel 3: G[b] = wA @ H[b] + bA  (M=512 in 64-tiles, N=128, K=512) -> bf16
// wA fp32 converted at staging
// ---------------------------------------------------------------------------
__global__ __launch_bounds__(256) void g_gemm_kernel(
    const float* __restrict__ wA, const float* __restrict__ bA,
    const float* __restrict__ H, __bf16* __restrict__ G)
{
  const int m0 = blockIdx.x * 64, b = blockIdx.y;
  const int tid = threadIdx.x, lane = tid & 63, w = tid >> 6;
  const int l15 = lane & 15, q = lane >> 4;

  __shared__ __attribute__((aligned(16))) __bf16 At[64*72];
  __shared__ __attribute__((aligned(16))) __bf16 Bt[128*72];
  f32x4 acc[4][2] = {};

  const float* Hb = H + (size_t)b*CIN*CN;
  const int colg = tid & 7, row0 = tid >> 3;
  const int nn = tid & 127, gh = tid >> 7;

  for (int k0 = 0; k0 < CIN; k0 += 64) {
    #pragma unroll
    for (int p = 0; p < 2; ++p) {
      int row = row0 + 32*p;
      cvt_store8(&At[row*72 + colg*8], wA + (size_t)(m0+row)*CIN + k0 + colg*8);
    }
    #pragma unroll
    for (int p = 0; p < 4; ++p) {
      int g = gh + 2*p;
      __attribute__((aligned(16))) __bf16 tmp[8];
      #pragma unroll
      for (int j = 0; j < 8; ++j)
        tmp[j] = (__bf16)Hb[(size_t)(k0 + g*8 + j)*CN + nn];
      *(uint4*)&Bt[nn*72 + g*8] = *(uint4*)tmp;
    }
    __syncthreads();
    #pragma unroll
    for (int kk = 0; kk < 2; ++kk) {
      short8 a[4], bb[2];
      #pragma unroll
      for (int mi = 0; mi < 4; ++mi)
        a[mi] = *(short8*)&At[(mi*16 + l15)*72 + kk*32 + q*8];
      #pragma unroll
      for (int ni = 0; ni < 2; ++ni)
        bb[ni] = *(short8*)&Bt[(w*32 + ni*16 + l15)*72 + kk*32 + q*8];
      #pragma unroll
      for (int mi = 0; mi < 4; ++mi)
        #pragma unroll
        for (int ni = 0; ni < 2; ++ni)
          acc[mi][ni] = MFMA(a[mi], bb[ni], acc[mi][ni]);
    }
    __syncthreads();
  }

  #pragma unroll
  for (int mi = 0; mi < 4; ++mi)
    #pragma unroll
    for (int ni = 0; ni < 2; ++ni)
      #pragma unroll
      for (int r = 0; r < 4; ++r) {
        int m = m0 + mi*16 + q*4 + r;
        int n = w*32 + ni*16 + l15;
        G[((size_t)b*CM + m)*CN + n] = (__bf16)(acc[mi][ni][r] + bA[m]);
      }
}

// ---------------------------------------------------------------------------
// Kernel 4: Z[b][m][s] = sum_n G[b][m][n] * attVT[b][s][n]  -> fp32 output
// ---------------------------------------------------------------------------
__global__ __launch_bounds__(256) void z_gemm_kernel(
    const __bf16* __restrict__ G, const __bf16* __restrict__ attVT,
    float* __restrict__ out)
{
  const int m0 = blockIdx.x * 128, s0 = blockIdx.y * 64, b = blockIdx.z;
  const int tid = threadIdx.x, lane = tid & 63, w = tid >> 6;
  const int l15 = lane & 15, q = lane >> 4;

  __shared__ __attribute__((aligned(16))) __bf16 At[128*136];
  __shared__ __attribute__((aligned(16))) __bf16 Bt[64*136];

  const __bf16* Gb = G + ((size_t)b*CM + m0)*CN;
  const __bf16* Vb = attVT + ((size_t)b*HW + s0)*CN;
  const int g = tid & 15, r0 = tid >> 4;
  #pragma unroll
  for (int p = 0; p < 8; ++p) {
    int row = r0 + 16*p;
    *(uint4*)&At[row*136 + g*8] = *(const uint4*)(Gb + (size_t)row*CN + g*8);
  }
  #pragma unroll
  for (int p = 0; p < 4; ++p) {
    int row = r0 + 16*p;
    *(uint4*)&Bt[row*136 + g*8] = *(const uint4*)(Vb + (size_t)row*CN + g*8);
  }
  __syncthreads();

  f32x4 acc[8] = {};
  #pragma unroll
  for (int kk = 0; kk < 4; ++kk) {
    short8 bb = *(short8*)&Bt[(w*16 + l15)*136 + kk*32 + q*8];
    #pragma unroll
    for (int mi = 0; mi < 8; ++mi) {
      short8 a = *(short8*)&At[(mi*16 + l15)*136 + kk*32 + q*8];
      acc[mi] = MFMA(a, bb, acc[mi]);
    }
  }

  const int s = s0 + w*16 + l15;
  #pragma unroll
  for (int mi = 0; mi < 8; ++mi)
    #pragma unroll
    for (int r = 0; r < 4; ++r) {
      int m = m0 + mi*16 + q*4 + r;
      out[((size_t)b*CM + m)*HW + s] = acc[mi][r];
    }
}

// ---------------------------------------------------------------------------
extern "C" void kernel_launch(void* const* d_in, const int* in_sizes, int n_in,
                              void* d_out, int out_size, void* d_ws, size_t ws_size,
                              hipStream_t stream)
{
  (void)in_sizes; (void)n_in; (void)out_size; (void)ws_size;
  const float* x  = (const float*)d_in[0];
  const float* wA = (const float*)d_in[1];
  const float* bA = (const float*)d_in[2];
  const float* wB = (const float*)d_in[3];
  const float* bB = (const float*)d_in[4];
  const float* wV = (const float*)d_in[5];
  const float* bV = (const float*)d_in[6];
  float* out = (float*)d_out;

  char* ws = (char*)d_ws;
  const size_t szBVB   = (size_t)BATCH*CN*HW*2;     // 12,845,056
  const size_t szAttVT = (size_t)BATCH*HW*CN*2;     // 12,845,056
  const size_t szH     = (size_t)BATCH*CIN*CN*4;    //  4,194,304
  const size_t szBsum  = (size_t)BATCH*CN*4;        //      8,192
  const size_t szG     = (size_t)BATCH*CM*CN*2;     //  2,097,152

  char* p = ws;
  __bf16* BVB   = (__bf16*)p; p += szBVB;
  __bf16* attVT = (__bf16*)p; p += szAttVT;
  float*  H     = (float*)p;  p += szH;
  float*  bsum  = (float*)p;  p += szBsum;   // contiguous with H -> one memset
  __bf16* G     = (__bf16*)p; p += szG;
  __bf16* Wimg  = (__bf16*)p;                // 8 x 36864 B = 294,912

  hipMemsetAsync(H, 0, szH + szBsum, stream);
  prep_w_kernel <<<dim3(32),      256, 0, stream>>>(wB, wV, Wimg);
  conv_bv_kernel<<<dim3(49,16),   256, 0, stream>>>(x, Wimg, bB, bV, BVB, attVT, bsum);
  h_gemm_kernel <<<dim3(4,16,7),  256, 0, stream>>>(x, BVB, bsum, H);
  g_gemm_kernel <<<dim3(8,16),    256, 0, stream>>>(wA, bA, H, G);
  z_gemm_kernel <<<dim3(4,49,16), 256, 0, stream>>>(G, attVT, out);
}